// Round 8
// baseline (411.574 us; speedup 1.0000x reference)
//
#include <hip/hip_runtime.h>
#include <hip/hip_bf16.h>

#define N_NODE 50000
#define NEDGE  600000
#define NRANGE 128
#define RSZ    391       // ceil(N_NODE / NRANGE); 128*391 = 50048 >= 50000
#define CAPB   6144      // slot capacity per (rel,range): mean 4688 + ~21 sigma
#define CHUNK  4096
#define NBLK1  147       // ceil(NEDGE / CHUNK)
#define SP1    (N_NODE * 32)   // partial-buffer stride (elements)

typedef __hip_bfloat16 bf16;
struct __attribute__((aligned(8))) bh4 { bf16 a, b, c, d; };
typedef __attribute__((ext_vector_type(8))) short short8;
typedef __attribute__((ext_vector_type(4))) float floatx4;

__device__ __forceinline__ short f2s(float f) {
    bf16 t = __float2bfloat16(f);
    return *(short*)&t;
}

// rel 0 = dd (dst=drug), 1 = gd (dst=drug), 2 = dg (dst=gene), 3 = gg (dst=gene)
// key packing: (bucket:7 << 25) | (dst_local:9 << 16) | (src:16)

// ---------- stage A: partition edges into fixed-capacity (rel,range) slots ----------
__global__ __launch_bounds__(256) void k_part(
    const int* __restrict__ d0, const int* __restrict__ s0,
    const int* __restrict__ d1, const int* __restrict__ s1,
    const int* __restrict__ d2, const int* __restrict__ s2,
    const int* __restrict__ d3, const int* __restrict__ s3,
    int* __restrict__ gcur, unsigned* __restrict__ gpart)
{
    __shared__ int hcur[NRANGE];
    __shared__ int delta[NRANGE];
    __shared__ int sc[256];
    __shared__ unsigned buf[CHUNK];
    int bid = blockIdx.x;
    int rel = bid / NBLK1;
    int c   = bid - rel * NBLK1;
    int tid = threadIdx.x;
    const int* dp = rel == 0 ? d0 : rel == 1 ? d1 : rel == 2 ? d2 : d3;
    const int* sp = rel == 0 ? s0 : rel == 1 ? s1 : rel == 2 ? s2 : s3;
    int e0 = c * CHUNK;
    int e1 = min(e0 + CHUNK, NEDGE);
    int cnt_chunk = e1 - e0;

    if (tid < NRANGE) hcur[tid] = 0;
    __syncthreads();
    for (int e = e0 + tid; e < e1; e += 256)
        atomicAdd(&hcur[dp[e] / RSZ], 1);
    __syncthreads();
    int v = (tid < NRANGE) ? hcur[tid] : 0;
    sc[tid] = v;
    __syncthreads();
    for (int d = 1; d < NRANGE; d <<= 1) {
        int t = (tid >= d && tid < NRANGE) ? sc[tid - d] : 0;
        __syncthreads();
        sc[tid] += t;
        __syncthreads();
    }
    if (tid < NRANGE) {
        int start = sc[tid] - v;
        int bg    = rel * NRANGE + tid;
        int resv  = atomicAdd(&gcur[bg], v);
        delta[tid] = bg * CAPB + resv - start;
        hcur[tid]  = start;
    }
    __syncthreads();
    for (int e = e0 + tid; e < e1; e += 256) {
        int d = dp[e];
        int b = d / RSZ;
        int p = atomicAdd(&hcur[b], 1);
        buf[p] = ((unsigned)b << 25) | ((unsigned)(d - b * RSZ) << 16) | (unsigned)sp[e];
    }
    __syncthreads();
    for (int i = tid; i < cnt_chunk; i += 256) {
        unsigned key = buf[i];
        gpart[delta[key >> 25] + i] = key;
    }
}

// ---------- stage B: per-rel exclusive scan of 512 bucket counts ----------
__global__ __launch_bounds__(512) void k_base(
    const int* __restrict__ gcur, int* __restrict__ base_rel)
{
    __shared__ int sc[512];
    int t = threadIdx.x;
    int v = gcur[t];
    sc[t] = v;
    __syncthreads();
    int loc = t & (NRANGE - 1);
    for (int d = 1; d < NRANGE; d <<= 1) {
        int x = (loc >= d) ? sc[t - d] : 0;
        __syncthreads();
        sc[t] += x;
        __syncthreads();
    }
    base_rel[t] = sc[t] - v;
}

// ---------- stage C: per (rel,range) block -> final CSR (off + edges) ----------
__global__ __launch_bounds__(256) void k_csr(
    const unsigned* __restrict__ gpart, const int* __restrict__ gcnt,
    const int* __restrict__ base_rel, int* __restrict__ off, int* __restrict__ edges)
{
    __shared__ int cur[RSZ];
    __shared__ unsigned short stg[CAPB];
    __shared__ int sc[256];
    int bid = blockIdx.x;
    int rel = bid >> 7, r = bid & (NRANGE - 1);
    int tid = threadIdx.x;
    int range0 = r * RSZ;
    int RS = min(RSZ, N_NODE - range0);
    if (RS < 0) RS = 0;
    int count = gcnt[bid];
    int base  = base_rel[bid];
    size_t slot0 = (size_t)bid * CAPB;

    for (int i = tid; i < RSZ; i += 256) cur[i] = 0;
    __syncthreads();
    for (int i = tid; i < count; i += 256)
        atomicAdd(&cur[(gpart[slot0 + i] >> 16) & 0x1FF], 1);
    __syncthreads();
    int vloc[2]; int run = 0;
#pragma unroll
    for (int j = 0; j < 2; j++) {
        int idx = tid * 2 + j;
        int x = (idx < RSZ) ? cur[idx] : 0;
        vloc[j] = x; run += x;
    }
    sc[tid] = run;
    __syncthreads();
    for (int d = 1; d < 256; d <<= 1) {
        int t = (tid >= d) ? sc[tid - d] : 0;
        __syncthreads();
        sc[tid] += t;
        __syncthreads();
    }
    int excl = sc[tid] - run;
    run = excl;
#pragma unroll
    for (int j = 0; j < 2; j++) {
        int idx = tid * 2 + j;
        if (idx < RSZ) { int x = vloc[j]; cur[idx] = run; run += x; }
    }
    __syncthreads();
    for (int i = tid; i < RS; i += 256)
        off[rel * (N_NODE + 1) + range0 + i] = base + cur[i];
    if (r == NRANGE - 1 && tid == 0) off[rel * (N_NODE + 1) + N_NODE] = NEDGE;
    __syncthreads();
    for (int i = tid; i < count; i += 256) {
        unsigned key = gpart[slot0 + i];
        int p = atomicAdd(&cur[(key >> 16) & 0x1FF], 1);
        stg[p] = (unsigned short)(key & 0xFFFFu);
    }
    __syncthreads();
    for (int i = tid; i < count; i += 256)
        edges[rel * NEDGE + base + i] = (int)stg[i];
}

// ---------- MFMA dual-weight GEMM pair: out(bf16) = X @ [Wa | Wb], 2 problems ----------
template <int K, int NOUT, bool AFP32>
__global__ __launch_bounds__(256) void k_gemm_pair(
    const void* __restrict__ X0, const void* __restrict__ X1,
    const float* __restrict__ Wa0, const float* __restrict__ Wb0,
    const float* __restrict__ Wa1, const float* __restrict__ Wb1,
    bf16* __restrict__ out0, bf16* __restrict__ out1, int M)
{
    constexpr int NB  = NOUT / 16;
    constexpr int KC  = K / 32;
    constexpr int NH  = NOUT / 2;
    constexpr int NBL = (NB == 8) ? 3 : 2;
    __shared__ short Wl[KC * NB * 512];

    int sel = blockIdx.y;
    const void*  X  = sel ? X1 : X0;
    const float* Wa = sel ? Wa1 : Wa0;
    const float* Wb = sel ? Wb1 : Wb0;
    bf16*        out = sel ? out1 : out0;

    int tid = threadIdx.x;
    for (int i = tid; i < KC * NB * 512; i += 256) {
        int j  = i & 7;
        int n  = (i >> 3) & 15;
        int q  = (i >> 7) & 3;
        int nb = (i >> 9) & (NB - 1);
        int kc = i >> (9 + NBL);
        int k  = kc * 32 + q * 8 + j;
        int c  = nb * 16 + n;
        float w = (c < NH) ? Wa[k * NH + c] : Wb[k * NH + (c - NH)];
        Wl[i] = f2s(w);
    }
    __syncthreads();

    int lane = tid & 63, wv = tid >> 6;
    int q = lane >> 4, lidx = lane & 15;
    int row0 = blockIdx.x * 64 + wv * 16;
    int rowA = min(row0 + lidx, M - 1);

    floatx4 acc[NB];
#pragma unroll
    for (int nb = 0; nb < NB; nb++) acc[nb] = (floatx4){0.f, 0.f, 0.f, 0.f};

#pragma unroll
    for (int kc = 0; kc < KC; kc++) {
        short8 a;
        if constexpr (AFP32) {
            const float* Xf = (const float*)X + (size_t)rowA * K + kc * 32 + q * 8;
            float4 f0 = *(const float4*)Xf;
            float4 f1 = *(const float4*)(Xf + 4);
            a[0] = f2s(f0.x); a[1] = f2s(f0.y); a[2] = f2s(f0.z); a[3] = f2s(f0.w);
            a[4] = f2s(f1.x); a[5] = f2s(f1.y); a[6] = f2s(f1.z); a[7] = f2s(f1.w);
        } else {
            a = *(const short8*)((const short*)X + (size_t)rowA * K + kc * 32 + q * 8);
        }
#pragma unroll
        for (int nb = 0; nb < NB; nb++) {
            short8 b = *(const short8*)&Wl[((kc * NB + nb) * 64 + lane) * 8];
            acc[nb] = __builtin_amdgcn_mfma_f32_16x16x32_bf16(a, b, acc[nb], 0, 0, 0);
        }
    }
#pragma unroll
    for (int nb = 0; nb < NB; nb++) {
#pragma unroll
        for (int r = 0; r < 4; r++) {
            int row = row0 + q * 4 + r;
            if (row < M)
                out[(size_t)row * NOUT + nb * 16 + lidx] = __float2bfloat16(acc[nb][r]);
        }
    }
}

// ---------- layer-1 gather, XCD-task partitioned ----------
// task t = blockIdx%8: rel r = t>>1, colhalf c = t&1. Working set = 50000 rows x 64 B
// = 3.2 MB -> fits one XCD's 4 MB L2 (block->XCD is round-robin on blockIdx).
// 8 lanes/edge x 8 B; 2x unrolled (16 edges in flight). Writes bf16 partial MEAN.
__global__ __launch_bounds__(256) void k_gtask1(
    const bf16* __restrict__ md1, const bf16* __restrict__ mg1,
    const int* __restrict__ off, const int* __restrict__ edges,
    bf16* __restrict__ p1)
{
    int b = blockIdx.x;
    int t = b & 7;
    int wv = threadIdx.x >> 6, lane = threadIdx.x & 63;
    int node = (b >> 3) * 4 + wv;
    if (node >= N_NODE) return;
    int r = t >> 1, c = t & 1;
    const bf16* M = (r == 0 || r == 2) ? md1 : mg1;
    int col0 = (r < 2 ? 0 : 64) + c * 32;
    const int* offr = off + r * (N_NODE + 1);
    const int* er   = edges + r * NEDGE;
    int beg = offr[node], end = offr[node + 1];
    int lgrp = lane >> 3, lidx = lane & 7;
    const unsigned* base = (const unsigned*)M + (col0 >> 1) + lidx * 2;
    float s0 = 0.f, s1 = 0.f, s2 = 0.f, s3 = 0.f;
    for (int e = beg; e < end; e += 64) {
        int nb = min(64, end - e);
        int eidx = (lane < nb) ? er[e + lane] : 0;
        int full = nb & ~15;
        int j = 0;
        for (; j < full; j += 16) {
            int sa = __shfl(eidx, j + lgrp);
            int sb = __shfl(eidx, j + 8 + lgrp);
            uint2 wa = *(const uint2*)(base + (size_t)sa * 64);
            uint2 wb = *(const uint2*)(base + (size_t)sb * 64);
            s0 += __uint_as_float(wa.x << 16);
            s1 += __uint_as_float(wa.x & 0xFFFF0000u);
            s2 += __uint_as_float(wa.y << 16);
            s3 += __uint_as_float(wa.y & 0xFFFF0000u);
            s0 += __uint_as_float(wb.x << 16);
            s1 += __uint_as_float(wb.x & 0xFFFF0000u);
            s2 += __uint_as_float(wb.y << 16);
            s3 += __uint_as_float(wb.y & 0xFFFF0000u);
        }
        for (; j < nb; j += 8) {
            int sa = __shfl(eidx, j + lgrp);
            float vm = (j + lgrp < nb) ? 1.f : 0.f;
            uint2 w = *(const uint2*)(base + (size_t)sa * 64);
            s0 += vm * __uint_as_float(w.x << 16);
            s1 += vm * __uint_as_float(w.x & 0xFFFF0000u);
            s2 += vm * __uint_as_float(w.y << 16);
            s3 += vm * __uint_as_float(w.y & 0xFFFF0000u);
        }
    }
    s0 += __shfl_xor(s0, 8); s0 += __shfl_xor(s0, 16); s0 += __shfl_xor(s0, 32);
    s1 += __shfl_xor(s1, 8); s1 += __shfl_xor(s1, 16); s1 += __shfl_xor(s1, 32);
    s2 += __shfl_xor(s2, 8); s2 += __shfl_xor(s2, 16); s2 += __shfl_xor(s2, 32);
    s3 += __shfl_xor(s3, 8); s3 += __shfl_xor(s3, 16); s3 += __shfl_xor(s3, 32);
    if (lane < 8) {
        float inv = 1.f / (float)max(end - beg, 1);
        bh4 v = { __float2bfloat16(s0 * inv), __float2bfloat16(s1 * inv),
                  __float2bfloat16(s2 * inv), __float2bfloat16(s3 * inv) };
        *(bh4*)(p1 + (size_t)t * SP1 + (size_t)node * 32 + lidx * 4) = v;
    }
}

// ---------- combine layer-1 partials -> hd, hg (bias + relu) ----------
__global__ __launch_bounds__(256) void k_combine1(
    const bf16* __restrict__ p1, const float* __restrict__ b1d,
    const float* __restrict__ b1g, bf16* __restrict__ hd, bf16* __restrict__ hg)
{
    int id = blockIdx.x * 256 + threadIdx.x;
    if (id >= 2 * N_NODE * 16) return;
    int half = id >= N_NODE * 16;
    int rem = id - half * N_NODE * 16;
    int n = rem >> 4, u = rem & 15;
    int f0 = u * 4, ch = u >> 3, fi = f0 & 31;
    const unsigned short* pa = (const unsigned short*)p1
        + ((size_t)((half ? 4 : 0) + ch)) * SP1 + (size_t)n * 32 + fi;
    const unsigned short* pb = (const unsigned short*)p1
        + ((size_t)((half ? 6 : 2) + ch)) * SP1 + (size_t)n * 32 + fi;
    uint2 wa = *(const uint2*)pa;
    uint2 wb = *(const uint2*)pb;
    const float* bias = (half ? b1g : b1d) + f0;
    float h0 = fmaxf(__uint_as_float(wa.x << 16)          + __uint_as_float(wb.x << 16)          + bias[0], 0.f);
    float h1 = fmaxf(__uint_as_float(wa.x & 0xFFFF0000u)  + __uint_as_float(wb.x & 0xFFFF0000u)  + bias[1], 0.f);
    float h2 = fmaxf(__uint_as_float(wa.y << 16)          + __uint_as_float(wb.y << 16)          + bias[2], 0.f);
    float h3 = fmaxf(__uint_as_float(wa.y & 0xFFFF0000u)  + __uint_as_float(wb.y & 0xFFFF0000u)  + bias[3], 0.f);
    bf16* h = half ? hg : hd;
    bh4 v = { __float2bfloat16(h0), __float2bfloat16(h1),
              __float2bfloat16(h2), __float2bfloat16(h3) };
    *(bh4*)(h + (size_t)n * 64 + f0) = v;
}

// ---------- layer-2 gather, XCD-task partitioned ----------
// task t = blockIdx%8: rel r = t>>1, node-half nh = t&1. Working set = 50000 x 64 B
// = 3.2 MB. Writes fp32 partial MEAN into p2[r].
__global__ __launch_bounds__(256) void k_gtask2(
    const bf16* __restrict__ md2, const bf16* __restrict__ mg2,
    const int* __restrict__ off, const int* __restrict__ edges,
    float* __restrict__ p2)
{
    int b = blockIdx.x;
    int t = b & 7;
    int wv = threadIdx.x >> 6, lane = threadIdx.x & 63;
    int r = t >> 1, nh = t & 1;
    int node = nh * (N_NODE / 2) + (b >> 3) * 4 + wv;
    int nend = nh * (N_NODE / 2) + N_NODE / 2;
    if (node >= nend) return;
    const bf16* M = (r == 0 || r == 2) ? md2 : mg2;
    int col0 = (r < 2) ? 0 : 32;
    const int* offr = off + r * (N_NODE + 1);
    const int* er   = edges + r * NEDGE;
    int beg = offr[node], end = offr[node + 1];
    int lgrp = lane >> 3, lidx = lane & 7;
    const unsigned* base = (const unsigned*)M + (col0 >> 1) + lidx * 2;
    float s0 = 0.f, s1 = 0.f, s2 = 0.f, s3 = 0.f;
    for (int e = beg; e < end; e += 64) {
        int nb = min(64, end - e);
        int eidx = (lane < nb) ? er[e + lane] : 0;
        int full = nb & ~15;
        int j = 0;
        for (; j < full; j += 16) {
            int sa = __shfl(eidx, j + lgrp);
            int sb = __shfl(eidx, j + 8 + lgrp);
            uint2 wa = *(const uint2*)(base + (size_t)sa * 32);
            uint2 wb = *(const uint2*)(base + (size_t)sb * 32);
            s0 += __uint_as_float(wa.x << 16);
            s1 += __uint_as_float(wa.x & 0xFFFF0000u);
            s2 += __uint_as_float(wa.y << 16);
            s3 += __uint_as_float(wa.y & 0xFFFF0000u);
            s0 += __uint_as_float(wb.x << 16);
            s1 += __uint_as_float(wb.x & 0xFFFF0000u);
            s2 += __uint_as_float(wb.y << 16);
            s3 += __uint_as_float(wb.y & 0xFFFF0000u);
        }
        for (; j < nb; j += 8) {
            int sa = __shfl(eidx, j + lgrp);
            float vm = (j + lgrp < nb) ? 1.f : 0.f;
            uint2 w = *(const uint2*)(base + (size_t)sa * 32);
            s0 += vm * __uint_as_float(w.x << 16);
            s1 += vm * __uint_as_float(w.x & 0xFFFF0000u);
            s2 += vm * __uint_as_float(w.y << 16);
            s3 += vm * __uint_as_float(w.y & 0xFFFF0000u);
        }
    }
    s0 += __shfl_xor(s0, 8); s0 += __shfl_xor(s0, 16); s0 += __shfl_xor(s0, 32);
    s1 += __shfl_xor(s1, 8); s1 += __shfl_xor(s1, 16); s1 += __shfl_xor(s1, 32);
    s2 += __shfl_xor(s2, 8); s2 += __shfl_xor(s2, 16); s2 += __shfl_xor(s2, 32);
    s3 += __shfl_xor(s3, 8); s3 += __shfl_xor(s3, 16); s3 += __shfl_xor(s3, 32);
    if (lane < 8) {
        float inv = 1.f / (float)max(end - beg, 1);
        float4 v = make_float4(s0 * inv, s1 * inv, s2 * inv, s3 * inv);
        *(float4*)(p2 + (size_t)r * SP1 + (size_t)node * 32 + lidx * 4) = v;
    }
}

// ---------- combine layer-2 partials -> out (fp32, + bias) ----------
__global__ __launch_bounds__(256) void k_combine2(
    const float* __restrict__ p2, const float* __restrict__ b2d,
    const float* __restrict__ b2g, float* __restrict__ out)
{
    int id = blockIdx.x * 256 + threadIdx.x;
    if (id >= 2 * N_NODE * 8) return;
    int half = id >= N_NODE * 8;
    int rem = id - half * N_NODE * 8;
    int n = rem >> 3, u = rem & 7;
    int f0 = u * 4;
    const float* pa = p2 + (size_t)(half ? 2 : 0) * SP1 + (size_t)n * 32 + f0;
    const float* pb = p2 + (size_t)(half ? 3 : 1) * SP1 + (size_t)n * 32 + f0;
    float4 va = *(const float4*)pa;
    float4 vb = *(const float4*)pb;
    const float* bias = (half ? b2g : b2d) + f0;
    float4 o = make_float4(va.x + vb.x + bias[0], va.y + vb.y + bias[1],
                           va.z + vb.z + bias[2], va.w + vb.w + bias[3]);
    size_t row = (half ? N_NODE : 0) + n;
    *(float4*)(out + row * 32 + f0) = o;
}

// ---------------- launcher ----------------
extern "C" void kernel_launch(void* const* d_in, const int* in_sizes, int n_in,
                              void* d_out, int out_size, void* d_ws, size_t ws_size,
                              hipStream_t stream)
{
    const float* xd = (const float*)d_in[0];
    const float* xg = (const float*)d_in[1];
    const int* dd_src = (const int*)d_in[2];  const int* dd_dst = (const int*)d_in[3];
    const int* dg_src = (const int*)d_in[4];  const int* dg_dst = (const int*)d_in[5];
    const int* gd_src = (const int*)d_in[6];  const int* gd_dst = (const int*)d_in[7];
    const int* gg_src = (const int*)d_in[8];  const int* gg_dst = (const int*)d_in[9];
    const float* W1dd = (const float*)d_in[10];
    const float* W1dg = (const float*)d_in[11];
    const float* W1gd = (const float*)d_in[12];
    const float* W1gg = (const float*)d_in[13];
    const float* b1d  = (const float*)d_in[14];
    const float* b1g  = (const float*)d_in[15];
    const float* W2dd = (const float*)d_in[16];
    const float* W2dg = (const float*)d_in[17];
    const float* W2gd = (const float*)d_in[18];
    const float* W2gg = (const float*)d_in[19];
    const float* b2d  = (const float*)d_in[20];
    const float* b2g  = (const float*)d_in[21];
    float* out = (float*)d_out;

    // workspace layout (~75 MB)
    int* gcur     = (int*)d_ws;                    // 512
    int* base_rel = gcur + 512;                    // 512
    int* off      = base_rel + 512;                // 4*(N_NODE+1)
    int* edges    = off + 4 * (N_NODE + 1);        // 4*NEDGE
    bf16* md1     = (bf16*)(edges + 4 * NEDGE);    // 50000*128 bf16 (12.8 MB)
    bf16* mg1     = md1 + (size_t)N_NODE * 128;
    bf16* p1      = mg1 + (size_t)N_NODE * 128;    // 8 * 50000*32 bf16 (25.6 MB)
    float* p2     = (float*)p1;                    // 4 * 50000*32 fp32 (25.6 MB), after p1 dead
    bf16* hd      = p1 + 8 * (size_t)SP1;          // 50000*64 bf16
    bf16* hg      = hd + (size_t)N_NODE * 64;
    bf16* md2     = md1;                           // md1/mg1 dead after gtask1
    bf16* mg2     = mg1;
    unsigned* gpart = (unsigned*)md1;              // 512*CAPB uints (12.6 MB), dead before GEMM1

    // ---- CSR build ----
    hipMemsetAsync(gcur, 0, 512 * sizeof(int), stream);
    k_part<<<4 * NBLK1, 256, 0, stream>>>(
        dd_dst, dd_src, gd_dst, gd_src, dg_dst, dg_src, gg_dst, gg_src, gcur, gpart);
    k_base<<<1, 512, 0, stream>>>(gcur, base_rel);
    k_csr<<<512, 256, 0, stream>>>(gpart, gcur, base_rel, off, edges);

    dim3 gemm_grid((N_NODE + 63) / 64, 2);

    // ---- layer 1 ----
    k_gemm_pair<128, 128, true><<<gemm_grid, 256, 0, stream>>>(
        xd, xg, W1dd, W1dg, W1gd, W1gg, md1, mg1, N_NODE);
    k_gtask1<<<8 * (N_NODE / 4), 256, 0, stream>>>(md1, mg1, off, edges, p1);
    k_combine1<<<(2 * N_NODE * 16) / 256, 256, 0, stream>>>(p1, b1d, b1g, hd, hg);

    // ---- layer 2 ----
    k_gemm_pair<64, 64, false><<<gemm_grid, 256, 0, stream>>>(
        hd, hg, W2dd, W2dg, W2gd, W2gg, md2, mg2, N_NODE);
    k_gtask2<<<8 * (N_NODE / 8), 256, 0, stream>>>(md2, mg2, off, edges, p2);
    k_combine2<<<(2 * N_NODE * 8) / 256, 256, 0, stream>>>(p2, b2d, b2g, out);
}

// Round 9
// 354.937 us; speedup vs baseline: 1.1596x; 1.1596x over previous
//
#include <hip/hip_runtime.h>
#include <hip/hip_bf16.h>

#define N_NODE 50000
#define NEDGE  600000
#define NRANGE 128
#define RSZ    391       // ceil(N_NODE / NRANGE); 128*391 = 50048 >= 50000
#define CAPB   6144      // slot capacity per (rel,range): mean 4688 + ~21 sigma
#define CHUNK  4096
#define NBLK1  147       // ceil(NEDGE / CHUNK)

typedef __hip_bfloat16 bf16;
typedef __attribute__((ext_vector_type(8))) short short8;
typedef __attribute__((ext_vector_type(4))) float floatx4;

__device__ __forceinline__ short f2s(float f) {
    bf16 t = __float2bfloat16(f);
    return *(short*)&t;
}
__device__ __forceinline__ unsigned pk2(float lo, float hi) {
    return ((unsigned)(unsigned short)f2s(lo)) | (((unsigned)(unsigned short)f2s(hi)) << 16);
}
__device__ __forceinline__ void acc2(float& a, float& b, unsigned w, float m) {
    a += m * __uint_as_float(w << 16);
    b += m * __uint_as_float(w & 0xFFFF0000u);
}

// rel 0 = dd (dst=drug), 1 = gd (dst=drug), 2 = dg (dst=gene), 3 = gg (dst=gene)
// key packing: (bucket:7 << 25) | (dst_local:9 << 16) | (src:16)

// ---------- stage A: partition edges into fixed-capacity (rel,range) slots ----------
__global__ __launch_bounds__(256) void k_part(
    const int* __restrict__ d0, const int* __restrict__ s0,
    const int* __restrict__ d1, const int* __restrict__ s1,
    const int* __restrict__ d2, const int* __restrict__ s2,
    const int* __restrict__ d3, const int* __restrict__ s3,
    int* __restrict__ gcur, unsigned* __restrict__ gpart)
{
    __shared__ int hcur[NRANGE];
    __shared__ int delta[NRANGE];
    __shared__ int sc[256];
    __shared__ unsigned buf[CHUNK];
    int bid = blockIdx.x;
    int rel = bid / NBLK1;
    int c   = bid - rel * NBLK1;
    int tid = threadIdx.x;
    const int* dp = rel == 0 ? d0 : rel == 1 ? d1 : rel == 2 ? d2 : d3;
    const int* sp = rel == 0 ? s0 : rel == 1 ? s1 : rel == 2 ? s2 : s3;
    int e0 = c * CHUNK;
    int e1 = min(e0 + CHUNK, NEDGE);
    int cnt_chunk = e1 - e0;

    if (tid < NRANGE) hcur[tid] = 0;
    __syncthreads();
    for (int e = e0 + tid; e < e1; e += 256)
        atomicAdd(&hcur[dp[e] / RSZ], 1);
    __syncthreads();
    int v = (tid < NRANGE) ? hcur[tid] : 0;
    sc[tid] = v;
    __syncthreads();
    for (int d = 1; d < NRANGE; d <<= 1) {
        int t = (tid >= d && tid < NRANGE) ? sc[tid - d] : 0;
        __syncthreads();
        sc[tid] += t;
        __syncthreads();
    }
    if (tid < NRANGE) {
        int start = sc[tid] - v;
        int bg    = rel * NRANGE + tid;
        int resv  = atomicAdd(&gcur[bg], v);
        delta[tid] = bg * CAPB + resv - start;
        hcur[tid]  = start;
    }
    __syncthreads();
    for (int e = e0 + tid; e < e1; e += 256) {
        int d = dp[e];
        int b = d / RSZ;
        int p = atomicAdd(&hcur[b], 1);
        buf[p] = ((unsigned)b << 25) | ((unsigned)(d - b * RSZ) << 16) | (unsigned)sp[e];
    }
    __syncthreads();
    for (int i = tid; i < cnt_chunk; i += 256) {
        unsigned key = buf[i];
        gpart[delta[key >> 25] + i] = key;
    }
}

// ---------- stage B: per-rel exclusive scan of 512 bucket counts ----------
__global__ __launch_bounds__(512) void k_base(
    const int* __restrict__ gcur, int* __restrict__ base_rel)
{
    __shared__ int sc[512];
    int t = threadIdx.x;
    int v = gcur[t];
    sc[t] = v;
    __syncthreads();
    int loc = t & (NRANGE - 1);
    for (int d = 1; d < NRANGE; d <<= 1) {
        int x = (loc >= d) ? sc[t - d] : 0;
        __syncthreads();
        sc[t] += x;
        __syncthreads();
    }
    base_rel[t] = sc[t] - v;
}

// ---------- stage C: per (rel,range) block -> final CSR (off + edges) ----------
__global__ __launch_bounds__(256) void k_csr(
    const unsigned* __restrict__ gpart, const int* __restrict__ gcnt,
    const int* __restrict__ base_rel, int* __restrict__ off, int* __restrict__ edges)
{
    __shared__ int cur[RSZ];
    __shared__ unsigned short stg[CAPB];
    __shared__ int sc[256];
    int bid = blockIdx.x;
    int rel = bid >> 7, r = bid & (NRANGE - 1);
    int tid = threadIdx.x;
    int range0 = r * RSZ;
    int RS = min(RSZ, N_NODE - range0);
    if (RS < 0) RS = 0;
    int count = gcnt[bid];
    int base  = base_rel[bid];
    size_t slot0 = (size_t)bid * CAPB;

    for (int i = tid; i < RSZ; i += 256) cur[i] = 0;
    __syncthreads();
    for (int i = tid; i < count; i += 256)
        atomicAdd(&cur[(gpart[slot0 + i] >> 16) & 0x1FF], 1);
    __syncthreads();
    int vloc[2]; int run = 0;
#pragma unroll
    for (int j = 0; j < 2; j++) {
        int idx = tid * 2 + j;
        int x = (idx < RSZ) ? cur[idx] : 0;
        vloc[j] = x; run += x;
    }
    sc[tid] = run;
    __syncthreads();
    for (int d = 1; d < 256; d <<= 1) {
        int t = (tid >= d) ? sc[tid - d] : 0;
        __syncthreads();
        sc[tid] += t;
        __syncthreads();
    }
    int excl = sc[tid] - run;
    run = excl;
#pragma unroll
    for (int j = 0; j < 2; j++) {
        int idx = tid * 2 + j;
        if (idx < RSZ) { int x = vloc[j]; cur[idx] = run; run += x; }
    }
    __syncthreads();
    for (int i = tid; i < RS; i += 256)
        off[rel * (N_NODE + 1) + range0 + i] = base + cur[i];
    if (r == NRANGE - 1 && tid == 0) off[rel * (N_NODE + 1) + N_NODE] = NEDGE;
    __syncthreads();
    for (int i = tid; i < count; i += 256) {
        unsigned key = gpart[slot0 + i];
        int p = atomicAdd(&cur[(key >> 16) & 0x1FF], 1);
        stg[p] = (unsigned short)(key & 0xFFFFu);
    }
    __syncthreads();
    for (int i = tid; i < count; i += 256)
        edges[rel * NEDGE + base + i] = (int)stg[i];
}

// ---------- MFMA dual-weight GEMM pair: out(bf16) = X @ [Wa | Wb], 2 problems ----------
template <int K, int NOUT, bool AFP32>
__global__ __launch_bounds__(256) void k_gemm_pair(
    const void* __restrict__ X0, const void* __restrict__ X1,
    const float* __restrict__ Wa0, const float* __restrict__ Wb0,
    const float* __restrict__ Wa1, const float* __restrict__ Wb1,
    bf16* __restrict__ out0, bf16* __restrict__ out1, int M)
{
    constexpr int NB  = NOUT / 16;
    constexpr int KC  = K / 32;
    constexpr int NH  = NOUT / 2;
    constexpr int NBL = (NB == 8) ? 3 : 2;
    __shared__ short Wl[KC * NB * 512];

    int sel = blockIdx.y;
    const void*  X  = sel ? X1 : X0;
    const float* Wa = sel ? Wa1 : Wa0;
    const float* Wb = sel ? Wb1 : Wb0;
    bf16*        out = sel ? out1 : out0;

    int tid = threadIdx.x;
    for (int i = tid; i < KC * NB * 512; i += 256) {
        int j  = i & 7;
        int n  = (i >> 3) & 15;
        int q  = (i >> 7) & 3;
        int nb = (i >> 9) & (NB - 1);
        int kc = i >> (9 + NBL);
        int k  = kc * 32 + q * 8 + j;
        int c  = nb * 16 + n;
        float w = (c < NH) ? Wa[k * NH + c] : Wb[k * NH + (c - NH)];
        Wl[i] = f2s(w);
    }
    __syncthreads();

    int lane = tid & 63, wv = tid >> 6;
    int q = lane >> 4, lidx = lane & 15;
    int row0 = blockIdx.x * 64 + wv * 16;
    int rowA = min(row0 + lidx, M - 1);

    floatx4 acc[NB];
#pragma unroll
    for (int nb = 0; nb < NB; nb++) acc[nb] = (floatx4){0.f, 0.f, 0.f, 0.f};

#pragma unroll
    for (int kc = 0; kc < KC; kc++) {
        short8 a;
        if constexpr (AFP32) {
            const float* Xf = (const float*)X + (size_t)rowA * K + kc * 32 + q * 8;
            float4 f0 = *(const float4*)Xf;
            float4 f1 = *(const float4*)(Xf + 4);
            a[0] = f2s(f0.x); a[1] = f2s(f0.y); a[2] = f2s(f0.z); a[3] = f2s(f0.w);
            a[4] = f2s(f1.x); a[5] = f2s(f1.y); a[6] = f2s(f1.z); a[7] = f2s(f1.w);
        } else {
            a = *(const short8*)((const short*)X + (size_t)rowA * K + kc * 32 + q * 8);
        }
#pragma unroll
        for (int nb = 0; nb < NB; nb++) {
            short8 b = *(const short8*)&Wl[((kc * NB + nb) * 64 + lane) * 8];
            acc[nb] = __builtin_amdgcn_mfma_f32_16x16x32_bf16(a, b, acc[nb], 0, 0, 0);
        }
    }
#pragma unroll
    for (int nb = 0; nb < NB; nb++) {
#pragma unroll
        for (int r = 0; r < 4; r++) {
            int row = row0 + q * 4 + r;
            if (row < M)
                out[(size_t)row * NOUT + nb * 16 + lidx] = __float2bfloat16(acc[nb][r]);
        }
    }
}

// ---------- seg-sum, 64 feat: 8 lanes/edge x 16 B, 4 loads in flight ----------
// base: uint* at (col + lidx*8 bf16); row stride 64 uints (128 B).
__device__ __forceinline__ void seg64(
    int beg, int end, const int* __restrict__ er,
    int lane, int lgrp, const unsigned* __restrict__ base, float s[8])
{
    for (int e = beg; e < end; e += 64) {
        int nb = min(64, end - e);
        int eidx = (lane < nb) ? er[e + lane] : 0;
        for (int j = 0; j < nb; j += 32) {
            int i0 = j + lgrp, i1 = i0 + 8, i2 = i0 + 16, i3 = i0 + 24;
            int sa0 = __shfl(eidx, i0);
            int sa1 = __shfl(eidx, i1);
            int sa2 = __shfl(eidx, i2);
            int sa3 = __shfl(eidx, i3);
            float m0 = (i0 < nb) ? 1.f : 0.f;
            float m1 = (i1 < nb) ? 1.f : 0.f;
            float m2 = (i2 < nb) ? 1.f : 0.f;
            float m3 = (i3 < nb) ? 1.f : 0.f;
            uint4 w0 = *(const uint4*)(base + (size_t)sa0 * 64);
            uint4 w1 = *(const uint4*)(base + (size_t)sa1 * 64);
            uint4 w2 = *(const uint4*)(base + (size_t)sa2 * 64);
            uint4 w3 = *(const uint4*)(base + (size_t)sa3 * 64);
            acc2(s[0], s[1], w0.x, m0); acc2(s[2], s[3], w0.y, m0);
            acc2(s[4], s[5], w0.z, m0); acc2(s[6], s[7], w0.w, m0);
            acc2(s[0], s[1], w1.x, m1); acc2(s[2], s[3], w1.y, m1);
            acc2(s[4], s[5], w1.z, m1); acc2(s[6], s[7], w1.w, m1);
            acc2(s[0], s[1], w2.x, m2); acc2(s[2], s[3], w2.y, m2);
            acc2(s[4], s[5], w2.z, m2); acc2(s[6], s[7], w2.w, m2);
            acc2(s[0], s[1], w3.x, m3); acc2(s[2], s[3], w3.y, m3);
            acc2(s[4], s[5], w3.z, m3); acc2(s[6], s[7], w3.w, m3);
        }
    }
}

// ---------- fused layer-1 gather: half 0 -> hd (cols 0), half 1 -> hg (cols 64) ----------
__global__ __launch_bounds__(256) void k_gather64x2(
    const bf16* __restrict__ m1, const bf16* __restrict__ m2,
    const int* __restrict__ offA0, const int* __restrict__ eA0,
    const int* __restrict__ offB0, const int* __restrict__ eB0,
    const float* __restrict__ bias0, bf16* __restrict__ out0,
    const int* __restrict__ offA1, const int* __restrict__ eA1,
    const int* __restrict__ offB1, const int* __restrict__ eB1,
    const float* __restrict__ bias1, bf16* __restrict__ out1)
{
    int gw   = (blockIdx.x * 256 + threadIdx.x) >> 6;
    int lane = threadIdx.x & 63;
    int half = (gw >= N_NODE);
    int wid  = gw - (half ? N_NODE : 0);
    const int* offA = half ? offA1 : offA0;
    const int* eA   = half ? eA1   : eA0;
    const int* offB = half ? offB1 : offB0;
    const int* eB   = half ? eB1   : eB0;
    const float* bias = half ? bias1 : bias0;
    bf16* out = half ? out1 : out0;
    int col = half ? 64 : 0;

    int lgrp = lane >> 3, lidx = lane & 7;
    const unsigned* base1 = (const unsigned*)m1 + (col >> 1) + lidx * 4;
    const unsigned* base2 = (const unsigned*)m2 + (col >> 1) + lidx * 4;

    int begA = offA[wid], endA = offA[wid + 1];
    int begB = offB[wid], endB = offB[wid + 1];
    float sA[8] = {0.f,0.f,0.f,0.f,0.f,0.f,0.f,0.f};
    float sB[8] = {0.f,0.f,0.f,0.f,0.f,0.f,0.f,0.f};
    seg64(begA, endA, eA, lane, lgrp, base1, sA);
    seg64(begB, endB, eB, lane, lgrp, base2, sB);
#pragma unroll
    for (int k = 0; k < 8; k++) {
        sA[k] += __shfl_xor(sA[k], 8); sA[k] += __shfl_xor(sA[k], 16); sA[k] += __shfl_xor(sA[k], 32);
        sB[k] += __shfl_xor(sB[k], 8); sB[k] += __shfl_xor(sB[k], 16); sB[k] += __shfl_xor(sB[k], 32);
    }
    if (lane < 8) {
        float ia = 1.f / (float)max(endA - begA, 1);
        float ib = 1.f / (float)max(endB - begB, 1);
        float h[8];
#pragma unroll
        for (int k = 0; k < 8; k++)
            h[k] = fmaxf(sA[k] * ia + sB[k] * ib + bias[lidx * 8 + k], 0.f);
        uint4 v;
        v.x = pk2(h[0], h[1]); v.y = pk2(h[2], h[3]);
        v.z = pk2(h[4], h[5]); v.w = pk2(h[6], h[7]);
        *(uint4*)(out + (size_t)wid * 64 + lidx * 8) = v;
    }
}

// ---------- seg-sum, 32 feat: 8 lanes/edge x 8 B, 4 loads in flight ----------
// base: uint* at (col + lidx*4 bf16); row stride 32 uints (64 B).
__device__ __forceinline__ void seg32(
    int beg, int end, const int* __restrict__ er,
    int lane, int lgrp, const unsigned* __restrict__ base, float s[4])
{
    for (int e = beg; e < end; e += 64) {
        int nb = min(64, end - e);
        int eidx = (lane < nb) ? er[e + lane] : 0;
        for (int j = 0; j < nb; j += 32) {
            int i0 = j + lgrp, i1 = i0 + 8, i2 = i0 + 16, i3 = i0 + 24;
            int sa0 = __shfl(eidx, i0);
            int sa1 = __shfl(eidx, i1);
            int sa2 = __shfl(eidx, i2);
            int sa3 = __shfl(eidx, i3);
            float m0 = (i0 < nb) ? 1.f : 0.f;
            float m1 = (i1 < nb) ? 1.f : 0.f;
            float m2 = (i2 < nb) ? 1.f : 0.f;
            float m3 = (i3 < nb) ? 1.f : 0.f;
            uint2 w0 = *(const uint2*)(base + (size_t)sa0 * 32);
            uint2 w1 = *(const uint2*)(base + (size_t)sa1 * 32);
            uint2 w2 = *(const uint2*)(base + (size_t)sa2 * 32);
            uint2 w3 = *(const uint2*)(base + (size_t)sa3 * 32);
            acc2(s[0], s[1], w0.x, m0); acc2(s[2], s[3], w0.y, m0);
            acc2(s[0], s[1], w1.x, m1); acc2(s[2], s[3], w1.y, m1);
            acc2(s[0], s[1], w2.x, m2); acc2(s[2], s[3], w2.y, m2);
            acc2(s[0], s[1], w3.x, m3); acc2(s[2], s[3], w3.y, m3);
        }
    }
}

// ---------- fused layer-2 gather: half 0 -> out[0:N] (cols 0), half 1 -> out[N:] (cols 32) ----------
__global__ __launch_bounds__(256) void k_gather32x2(
    const bf16* __restrict__ m1, const bf16* __restrict__ m2,
    const int* __restrict__ offA0, const int* __restrict__ eA0,
    const int* __restrict__ offB0, const int* __restrict__ eB0,
    const float* __restrict__ bias0, float* __restrict__ out0,
    const int* __restrict__ offA1, const int* __restrict__ eA1,
    const int* __restrict__ offB1, const int* __restrict__ eB1,
    const float* __restrict__ bias1, float* __restrict__ out1)
{
    int gw   = (blockIdx.x * 256 + threadIdx.x) >> 6;
    int lane = threadIdx.x & 63;
    int half = (gw >= N_NODE);
    int wid  = gw - (half ? N_NODE : 0);
    const int* offA = half ? offA1 : offA0;
    const int* eA   = half ? eA1   : eA0;
    const int* offB = half ? offB1 : offB0;
    const int* eB   = half ? eB1   : eB0;
    const float* bias = half ? bias1 : bias0;
    float* out = half ? out1 : out0;
    int col = half ? 32 : 0;

    int lgrp = lane >> 3, lidx = lane & 7;
    const unsigned* base1 = (const unsigned*)m1 + (col >> 1) + lidx * 2;
    const unsigned* base2 = (const unsigned*)m2 + (col >> 1) + lidx * 2;

    int begA = offA[wid], endA = offA[wid + 1];
    int begB = offB[wid], endB = offB[wid + 1];
    float sA[4] = {0.f, 0.f, 0.f, 0.f}, sB[4] = {0.f, 0.f, 0.f, 0.f};
    seg32(begA, endA, eA, lane, lgrp, base1, sA);
    seg32(begB, endB, eB, lane, lgrp, base2, sB);
#pragma unroll
    for (int k = 0; k < 4; k++) {
        sA[k] += __shfl_xor(sA[k], 8); sA[k] += __shfl_xor(sA[k], 16); sA[k] += __shfl_xor(sA[k], 32);
        sB[k] += __shfl_xor(sB[k], 8); sB[k] += __shfl_xor(sB[k], 16); sB[k] += __shfl_xor(sB[k], 32);
    }
    if (lane < 8) {
        float ia = 1.f / (float)max(endA - begA, 1);
        float ib = 1.f / (float)max(endB - begB, 1);
        float4 v;
        v.x = sA[0] * ia + sB[0] * ib + bias[lidx * 4 + 0];
        v.y = sA[1] * ia + sB[1] * ib + bias[lidx * 4 + 1];
        v.z = sA[2] * ia + sB[2] * ib + bias[lidx * 4 + 2];
        v.w = sA[3] * ia + sB[3] * ib + bias[lidx * 4 + 3];
        *(float4*)(out + (size_t)wid * 32 + lidx * 4) = v;
    }
}

// ---------------- launcher ----------------
extern "C" void kernel_launch(void* const* d_in, const int* in_sizes, int n_in,
                              void* d_out, int out_size, void* d_ws, size_t ws_size,
                              hipStream_t stream)
{
    const float* xd = (const float*)d_in[0];
    const float* xg = (const float*)d_in[1];
    const int* dd_src = (const int*)d_in[2];  const int* dd_dst = (const int*)d_in[3];
    const int* dg_src = (const int*)d_in[4];  const int* dg_dst = (const int*)d_in[5];
    const int* gd_src = (const int*)d_in[6];  const int* gd_dst = (const int*)d_in[7];
    const int* gg_src = (const int*)d_in[8];  const int* gg_dst = (const int*)d_in[9];
    const float* W1dd = (const float*)d_in[10];
    const float* W1dg = (const float*)d_in[11];
    const float* W1gd = (const float*)d_in[12];
    const float* W1gg = (const float*)d_in[13];
    const float* b1d  = (const float*)d_in[14];
    const float* b1g  = (const float*)d_in[15];
    const float* W2dd = (const float*)d_in[16];
    const float* W2dg = (const float*)d_in[17];
    const float* W2gd = (const float*)d_in[18];
    const float* W2gg = (const float*)d_in[19];
    const float* b2d  = (const float*)d_in[20];
    const float* b2g  = (const float*)d_in[21];
    float* out = (float*)d_out;

    // workspace layout
    int* gcur     = (int*)d_ws;                    // 512
    int* base_rel = gcur + 512;                    // 512
    int* off      = base_rel + 512;                // 4*(N_NODE+1)
    int* edges    = off + 4 * (N_NODE + 1);        // 4*NEDGE
    bf16* md1     = (bf16*)(edges + 4 * NEDGE);    // 50000*128 bf16 (12.8 MB)
    bf16* mg1     = md1 + (size_t)N_NODE * 128;
    bf16* hd      = mg1 + (size_t)N_NODE * 128;    // 50000*64 bf16
    bf16* hg      = hd + (size_t)N_NODE * 64;
    bf16* md2     = md1;
    bf16* mg2     = mg1;
    unsigned* gpart = (unsigned*)md1;              // 512*CAPB uints (12.6 MB), dead before GEMM1

    // ---- CSR build ----
    hipMemsetAsync(gcur, 0, 512 * sizeof(int), stream);
    k_part<<<4 * NBLK1, 256, 0, stream>>>(
        dd_dst, dd_src, gd_dst, gd_src, dg_dst, dg_src, gg_dst, gg_src, gcur, gpart);
    k_base<<<1, 512, 0, stream>>>(gcur, base_rel);
    k_csr<<<512, 256, 0, stream>>>(gpart, gcur, base_rel, off, edges);

    const int* off_dd = off + 0 * (N_NODE + 1);
    const int* off_gd = off + 1 * (N_NODE + 1);
    const int* off_dg = off + 2 * (N_NODE + 1);
    const int* off_gg = off + 3 * (N_NODE + 1);
    const int* e_dd = edges + 0 * NEDGE;
    const int* e_gd = edges + 1 * NEDGE;
    const int* e_dg = edges + 2 * NEDGE;
    const int* e_gg = edges + 3 * NEDGE;

    dim3 gemm_grid((N_NODE + 63) / 64, 2);
    int gather_grid = 2 * N_NODE / 4;   // 2*N waves, 4 waves/block

    // ---- layer 1 ----
    k_gemm_pair<128, 128, true><<<gemm_grid, 256, 0, stream>>>(
        xd, xg, W1dd, W1dg, W1gd, W1gg, md1, mg1, N_NODE);
    k_gather64x2<<<gather_grid, 256, 0, stream>>>(
        md1, mg1,
        off_dd, e_dd, off_gd, e_gd, b1d, hd,
        off_dg, e_dg, off_gg, e_gg, b1g, hg);

    // ---- layer 2 ----
    k_gemm_pair<64, 64, false><<<gemm_grid, 256, 0, stream>>>(
        hd, hg, W2dd, W2dg, W2gd, W2gg, md2, mg2, N_NODE);
    k_gather32x2<<<gather_grid, 256, 0, stream>>>(
        md2, mg2,
        off_dd, e_dd, off_gd, e_gd, b2d, out,
        off_dg, e_dg, off_gg, e_gg, b2g, out + (size_t)N_NODE * 32);
}